// Round 6
// baseline (403.176 us; speedup 1.0000x reference)
//
#include <hip/hip_runtime.h>

#define N_NODES 20000
#define N_PAD   20032            // 313 * 64
#define N_EDGES 200000
#define ETOT    (N_EDGES + N_NODES)
#define F_IN    20
#define HID     128
#define HEADS   4
#define FTOT    (HEADS * HID)   // 512
#define LAYERS  4
#define NGRAPH  32
#define NEG_SLOPE 0.2f

typedef __attribute__((ext_vector_type(8))) unsigned short ushortx8;
typedef __attribute__((ext_vector_type(8))) short short8;
typedef __attribute__((ext_vector_type(4))) float f32x4;

static __device__ __forceinline__ unsigned short f2bf(float f) {
    unsigned u = __float_as_uint(f);
    u += 0x7FFFu + ((u >> 16) & 1u);   // round-to-nearest-even
    return (unsigned short)(u >> 16);
}
static __device__ __forceinline__ float bf2f(unsigned short s) {
    return __uint_as_float(((unsigned)s) << 16);
}

// ---------------- CSR build (dst is layer-invariant) ----------------

__global__ void k_hist(const int* __restrict__ ei, int* __restrict__ deg) {
    int i = blockIdx.x * blockDim.x + threadIdx.x;
    if (i >= ETOT) return;
    int d = (i < N_EDGES) ? ei[N_EDGES + i] : (i - N_EDGES);
    atomicAdd(&deg[d], 1);
}

__global__ __launch_bounds__(1024) void k_scan(const int* __restrict__ deg, int* __restrict__ off) {
    __shared__ int wsum[16];
    __shared__ int carry_s;
    int tid  = threadIdx.x;
    int lane = tid & 63, wv = tid >> 6;
    if (tid == 0) carry_s = 0;
    __syncthreads();
    for (int base = 0; base < N_NODES; base += 1024) {
        int idx = base + tid;
        int v = (idx < N_NODES) ? deg[idx] : 0;
        int x = v;
        #pragma unroll
        for (int s = 1; s < 64; s <<= 1) {
            int t = __shfl_up(x, s, 64);
            if (lane >= s) x += t;
        }
        if (lane == 63) wsum[wv] = x;
        __syncthreads();
        if (wv == 0) {
            int ws = (lane < 16) ? wsum[lane] : 0;
            #pragma unroll
            for (int s = 1; s < 16; s <<= 1) {
                int t = __shfl_up(ws, s, 64);
                if (lane >= s) ws += t;
            }
            if (lane < 16) wsum[lane] = ws;
        }
        __syncthreads();
        int wprev = (wv == 0) ? 0 : wsum[wv - 1];
        int incl  = carry_s + wprev + x;
        if (idx < N_NODES) off[idx] = incl - v;
        __syncthreads();
        if (tid == 1023) carry_s = incl;
        __syncthreads();
    }
    if (threadIdx.x == 0) off[N_NODES] = carry_s;
}

__global__ void k_scatter(const int* __restrict__ ei, const int* __restrict__ off,
                          int* __restrict__ cur, int* __restrict__ csr_src) {
    int i = blockIdx.x * blockDim.x + threadIdx.x;
    if (i >= ETOT) return;
    int s, d;
    if (i < N_EDGES) { s = ei[i]; d = ei[N_EDGES + i]; }
    else             { s = d = i - N_EDGES; }
    int pos = off[d] + atomicAdd(&cur[d], 1);
    csr_src[pos] = s;
}

// ---------------- graph boundaries (batch is sorted): no atomics ----------------

__global__ void k_bounds(const int* __restrict__ batch, int* __restrict__ gstart) {
    int i = blockIdx.x * blockDim.x + threadIdx.x;
    if (i >= N_NODES) return;
    int b = batch[i];
    int prev = (i == 0) ? -1 : batch[i - 1];
    for (int g = prev + 1; g <= b; ++g) gstart[g] = i;
    if (i == N_NODES - 1) {
        for (int g = b + 1; g <= NGRAPH; ++g) gstart[g] = N_NODES;
    }
}

// ---------------- W pre-swizzle: gat_W fp32 -> bf16 MFMA-fragment order ----------------
// layout: [l][cg(32)][kc(4)][lane(64)][e(8)],
// value = W[l][kc*32 + (lane>>4)*8 + e][cg*16 + (lane&15)]

__global__ void k_wconv(const float* __restrict__ W, unsigned short* __restrict__ wswz) {
    int o = blockIdx.x * 256 + threadIdx.x;
    if (o >= LAYERS * 32 * 4 * 64 * 8) return;
    int e    = o & 7;
    int lane = (o >> 3) & 63;
    int kc   = (o >> 9) & 3;
    int cg   = (o >> 11) & 31;
    int l    = o >> 16;
    int k    = kc * 32 + (lane >> 4) * 8 + e;
    int col  = cg * 16 + (lane & 15);
    wswz[o] = f2bf(W[((size_t)l * HID + k) * FTOT + col]);
}

// ---------------- input projection: h = relu(x @ W_in + b_in), + bf16 shadow ----------------

__global__ __launch_bounds__(256) void k_inproj(const float* __restrict__ x,
                                                const float* __restrict__ W,
                                                const float* __restrict__ b,
                                                float* __restrict__ h,
                                                unsigned short* __restrict__ hb) {
    __shared__ float xs[2][F_IN];
    int tid = threadIdx.x;
    int node0 = blockIdx.x * 2;
    if (tid < 2 * F_IN) {
        int r = tid / F_IN, k = tid % F_IN;
        int nd = node0 + r;
        xs[r][k] = (nd < N_NODES) ? x[nd * F_IN + k] : 0.f;
    }
    __syncthreads();
    int ln = tid >> 7;
    int c  = tid & 127;
    int node = node0 + ln;
    if (node >= N_NODES) return;
    float s = b[c];
    #pragma unroll
    for (int k = 0; k < F_IN; ++k) s += xs[ln][k] * W[k * HID + c];
    float r = fmaxf(s, 0.f);
    h[(size_t)node * HID + c] = r;
    hb[(size_t)node * HID + c] = f2bf(r);
}

// ---------------- GEMM (MFMA) + fused attention dots ----------------
// grid (N_PAD/64, HEADS); block 256 = 4 waves; wave w: rows [bx*64+w*16,+16),
// cols [hd*128, +128). al_s/al_d written by plain stores (one block per node,head).

__global__ __launch_bounds__(256) void k_gemm(const unsigned short* __restrict__ hb,
                                              const unsigned short* __restrict__ wswz,
                                              const float* __restrict__ asrc,
                                              const float* __restrict__ adst,
                                              unsigned short* __restrict__ xl,
                                              float* __restrict__ al_s,
                                              float* __restrict__ al_d) {
    int tid  = threadIdx.x;
    int lane = tid & 63;
    int w    = tid >> 6;
    int r0   = blockIdx.x * 64 + w * 16;
    int hd   = blockIdx.y;
    int arow = r0 + (lane & 15);
    const short8* ap = (const short8*)(hb + (size_t)arow * HID + (lane >> 4) * 8);
    const short8* bp = (const short8*)wswz;
    short8 a[4];
    #pragma unroll
    for (int kc = 0; kc < 4; ++kc) a[kc] = ap[kc * 4];   // kc*32 channels
    f32x4 acc[8];
    #pragma unroll
    for (int ct = 0; ct < 8; ++ct) {
        f32x4 c = {0.f, 0.f, 0.f, 0.f};
        int cg = hd * 8 + ct;
        #pragma unroll
        for (int kc = 0; kc < 4; ++kc) {
            short8 b = bp[(cg * 4 + kc) * 64 + lane];
            c = __builtin_amdgcn_mfma_f32_16x16x32_bf16(a[kc], b, c, 0, 0, 0);
        }
        acc[ct] = c;
    }
    int ocol = lane & 15;
    int orow = r0 + (lane >> 4) * 4;
    float vs[4] = {}, vd[4] = {};
    #pragma unroll
    for (int ct = 0; ct < 8; ++ct) {
        int colg = hd * 128 + ct * 16 + ocol;
        float as = asrc[colg], ad = adst[colg];
        #pragma unroll
        for (int r = 0; r < 4; ++r) {
            vs[r] += acc[ct][r] * as;
            vd[r] += acc[ct][r] * ad;
            int row = orow + r;
            if (row < N_NODES) xl[(size_t)row * FTOT + colg] = f2bf(acc[ct][r]);
        }
    }
    #pragma unroll
    for (int msk = 1; msk < 16; msk <<= 1) {
        #pragma unroll
        for (int r = 0; r < 4; ++r) {
            vs[r] += __shfl_xor(vs[r], msk, 64);
            vd[r] += __shfl_xor(vd[r], msk, 64);
        }
    }
    if (ocol == 0) {
        #pragma unroll
        for (int r = 0; r < 4; ++r) {
            int row = orow + r;
            if (row < N_NODES) {
                al_s[row * HEADS + hd] = vs[r];
                al_d[row * HEADS + hd] = vd[r];
            }
        }
    }
}

// ---------------- edge aggregation (segment softmax + weighted sum) ----------------
// block 256 = 4 waves = 2 nodes; wave pair per node, each wave owns 256 channels
// (2 heads); lane owns 4 channels; 2-edge software pipeline.

__global__ __launch_bounds__(256) void k_agg(const unsigned short* __restrict__ xl,
                                             const float* __restrict__ al_s,
                                             const float* __restrict__ al_d,
                                             const int* __restrict__ csr_off,
                                             const int* __restrict__ csr_src,
                                             const float* __restrict__ bias,
                                             float* __restrict__ h,
                                             unsigned short* __restrict__ hb) {
    __shared__ float buf[2][HID];
    int tid   = threadIdx.x;
    int lane  = tid & 63;
    int w     = tid >> 6;
    int nip   = w >> 1;                 // node within block
    int chalf = w & 1;                  // channel half (heads 2c..2c+1)
    int node  = blockIdx.x * 2 + nip;
    int hh    = chalf * 2 + (lane >> 5);
    int e0 = csr_off[node], e1 = csr_off[node + 1];
    float ald = al_d[node * HEADS + hh];

    // pass A: online (m,z), 32 edge-lanes per head
    float m = -1e30f, z = 0.f;
    for (int e = e0 + (lane & 31); e < e1; e += 32) {
        int s = csr_src[e];
        float ev = al_s[s * HEADS + hh] + ald;
        ev = ev > 0.f ? ev : NEG_SLOPE * ev;
        float mn = fmaxf(m, ev);
        z = z * __expf(m - mn) + __expf(ev - mn);
        m = mn;
    }
    #pragma unroll
    for (int msk = 1; msk < 32; msk <<= 1) {
        float m2 = __shfl_xor(m, msk, 64);
        float z2 = __shfl_xor(z, msk, 64);
        float mn = fmaxf(m, m2);
        z = z * __expf(m - mn) + z2 * __expf(m2 - mn);
        m = mn;
    }
    float zinv = 1.f / (z + 1e-16f);

    // pass B: 2-edge pipelined weighted gather, 8 B/lane/edge
    float acc0 = 0.f, acc1 = 0.f, acc2 = 0.f, acc3 = 0.f;
    const unsigned short* xbase = xl + chalf * 256 + lane * 4;
    int e = e0;
    for (; e + 1 < e1; e += 2) {
        int s0 = csr_src[e], s1 = csr_src[e + 1];
        float ev0 = al_s[s0 * HEADS + hh] + ald;
        float ev1 = al_s[s1 * HEADS + hh] + ald;
        ushort4 v0 = *(const ushort4*)(xbase + (size_t)s0 * FTOT);
        ushort4 v1 = *(const ushort4*)(xbase + (size_t)s1 * FTOT);
        ev0 = ev0 > 0.f ? ev0 : NEG_SLOPE * ev0;
        ev1 = ev1 > 0.f ? ev1 : NEG_SLOPE * ev1;
        float a0 = __expf(ev0 - m) * zinv;
        float a1 = __expf(ev1 - m) * zinv;
        acc0 += a0 * bf2f(v0.x) + a1 * bf2f(v1.x);
        acc1 += a0 * bf2f(v0.y) + a1 * bf2f(v1.y);
        acc2 += a0 * bf2f(v0.z) + a1 * bf2f(v1.z);
        acc3 += a0 * bf2f(v0.w) + a1 * bf2f(v1.w);
    }
    if (e < e1) {
        int s0 = csr_src[e];
        float ev0 = al_s[s0 * HEADS + hh] + ald;
        ushort4 v0 = *(const ushort4*)(xbase + (size_t)s0 * FTOT);
        ev0 = ev0 > 0.f ? ev0 : NEG_SLOPE * ev0;
        float a0 = __expf(ev0 - m) * zinv;
        acc0 += a0 * bf2f(v0.x);
        acc1 += a0 * bf2f(v0.y);
        acc2 += a0 * bf2f(v0.z);
        acc3 += a0 * bf2f(v0.w);
    }
    // sum the wave's two heads: lanes l and l^32 share within-head channel
    acc0 += __shfl_xor(acc0, 32, 64);
    acc1 += __shfl_xor(acc1, 32, 64);
    acc2 += __shfl_xor(acc2, 32, 64);
    acc3 += __shfl_xor(acc3, 32, 64);
    if (chalf == 1 && lane < 32) {
        int c = lane * 4;
        buf[nip][c]     = acc0;
        buf[nip][c + 1] = acc1;
        buf[nip][c + 2] = acc2;
        buf[nip][c + 3] = acc3;
    }
    __syncthreads();
    if (chalf == 0 && lane < 32) {
        int c = lane * 4;
        float4 hv = *(const float4*)(h + (size_t)node * HID + c);
        float4 bb = *(const float4*)(bias + c);
        float o0 = fmaxf((acc0 + buf[nip][c])     * 0.25f + bb.x, 0.f) + hv.x;
        float o1 = fmaxf((acc1 + buf[nip][c + 1]) * 0.25f + bb.y, 0.f) + hv.y;
        float o2 = fmaxf((acc2 + buf[nip][c + 2]) * 0.25f + bb.z, 0.f) + hv.z;
        float o3 = fmaxf((acc3 + buf[nip][c + 3]) * 0.25f + bb.w, 0.f) + hv.w;
        *(float4*)(h + (size_t)node * HID + c) = make_float4(o0, o1, o2, o3);
        ushort4 hv16;
        hv16.x = f2bf(o0); hv16.y = f2bf(o1); hv16.z = f2bf(o2); hv16.w = f2bf(o3);
        *(ushort4*)(hb + (size_t)node * HID + c) = hv16;
    }
}

// ---------------- pooling + MLP ----------------

__global__ __launch_bounds__(128) void k_pool(const float* __restrict__ h,
                                              const int* __restrict__ gstart,
                                              float* __restrict__ pooled) {
    int g = blockIdx.y;
    int slice = blockIdx.x;      // 0..31
    int tid = threadIdx.x;       // 0..127
    int start = gstart[g];
    int cnt   = gstart[g + 1] - start;
    int per = (cnt + 31) / 32;
    int r0 = slice * per, r1 = min(r0 + per, cnt);
    if (r0 >= r1) return;
    float s0 = 0.f, s1 = 0.f, s2 = 0.f, s3 = 0.f;
    int r = r0;
    for (; r + 3 < r1; r += 4) {
        s0 += h[(size_t)(start + r)     * HID + tid];
        s1 += h[(size_t)(start + r + 1) * HID + tid];
        s2 += h[(size_t)(start + r + 2) * HID + tid];
        s3 += h[(size_t)(start + r + 3) * HID + tid];
    }
    for (; r < r1; ++r) s0 += h[(size_t)(start + r) * HID + tid];
    atomicAdd(&pooled[g * HID + tid], (s0 + s1) + (s2 + s3));
}

// one block per graph; 256 threads; k-split partials reduced in LDS
__global__ __launch_bounds__(256) void k_mlp(const float* __restrict__ pooled,
                                             const int* __restrict__ gstart,
                                             const float* __restrict__ W1, const float* __restrict__ b1,
                                             const float* __restrict__ W2, const float* __restrict__ b2,
                                             const float* __restrict__ W3, const float* __restrict__ b3,
                                             float* __restrict__ out) {
    int gr = blockIdx.x;
    __shared__ float g[HID];
    __shared__ float part[4][64];
    __shared__ float t1[64], t2[64];
    int tid = threadIdx.x;
    if (tid < HID) {
        float inv = 1.f / fmaxf((float)(gstart[gr + 1] - gstart[gr]), 1.f);
        g[tid] = pooled[gr * HID + tid] * inv;
    }
    __syncthreads();
    {
        int c = tid & 63, q = tid >> 6;
        float s = 0.f;
        #pragma unroll 8
        for (int k = q * 32; k < q * 32 + 32; ++k) s += g[k] * W1[k * 64 + c];
        part[q][c] = s;
        __syncthreads();
        if (tid < 64) t1[tid] = fmaxf(part[0][tid] + part[1][tid] + part[2][tid] + part[3][tid] + b1[tid], 0.f);
        __syncthreads();
    }
    {
        int c = tid & 63, q = tid >> 6;
        float s = 0.f;
        #pragma unroll 8
        for (int k = q * 16; k < q * 16 + 16; ++k) s += t1[k] * W2[k * 64 + c];
        part[q][c] = s;
        __syncthreads();
        if (tid < 64) t2[tid] = fmaxf(part[0][tid] + part[1][tid] + part[2][tid] + part[3][tid] + b2[tid], 0.f);
        __syncthreads();
    }
    {
        int c = tid & 31, q = tid >> 5;
        float s = 0.f;
        #pragma unroll 8
        for (int k = q * 8; k < q * 8 + 8; ++k) s += t2[k] * W3[k * 32 + c];
        float* pf = &part[0][0];
        pf[q * 32 + c] = s;
        __syncthreads();
        if (tid < 32) {
            float r = b3[tid];
            #pragma unroll
            for (int q2 = 0; q2 < 8; ++q2) r += pf[q2 * 32 + tid];
            out[gr * 32 + tid] = r;
        }
    }
}

// ---------------- launcher ----------------

extern "C" void kernel_launch(void* const* d_in, const int* in_sizes, int n_in,
                              void* d_out, int out_size, void* d_ws, size_t ws_size,
                              hipStream_t stream) {
    const float* x       = (const float*)d_in[0];
    const int*   ei      = (const int*)d_in[1];
    const int*   batch   = (const int*)d_in[2];
    const float* W_in    = (const float*)d_in[3];
    const float* b_in    = (const float*)d_in[4];
    const float* gat_W   = (const float*)d_in[5];
    const float* att_src = (const float*)d_in[6];
    const float* att_dst = (const float*)d_in[7];
    const float* gat_b   = (const float*)d_in[8];
    const float* W1 = (const float*)d_in[9];
    const float* b1 = (const float*)d_in[10];
    const float* W2 = (const float*)d_in[11];
    const float* b2 = (const float*)d_in[12];
    const float* W3 = (const float*)d_in[13];
    const float* b3 = (const float*)d_in[14];
    float* out = (float*)d_out;

    char* ws = (char*)d_ws;
    size_t o = 0;
    auto alloc = [&](size_t nbytes) -> void* {
        void* p = ws + o;
        o += (nbytes + 255) & ~(size_t)255;
        return p;
    };
    int* deg      = (int*)alloc((size_t)2 * N_NODES * 4);      // deg | cur
    int* cur      = deg + N_NODES;
    int* gstart   = (int*)alloc((size_t)(NGRAPH + 1) * 4);
    float* pooled = (float*)alloc((size_t)NGRAPH * HID * 4);
    int* csr_off  = (int*)alloc((size_t)(N_NODES + 1) * 4);
    int* csr_src  = (int*)alloc((size_t)ETOT * 4);
    float* h      = (float*)alloc((size_t)N_NODES * HID * 4);
    unsigned short* hb   = (unsigned short*)alloc((size_t)N_PAD * HID * 2);
    unsigned short* xl   = (unsigned short*)alloc((size_t)N_NODES * FTOT * 2);
    unsigned short* wswz = (unsigned short*)alloc((size_t)LAYERS * HID * FTOT * 2);
    float* al_s   = (float*)alloc((size_t)N_NODES * HEADS * 4);
    float* al_d   = (float*)alloc((size_t)N_NODES * HEADS * 4);

    hipMemsetAsync(deg, 0, (size_t)2 * N_NODES * 4, stream);
    hipMemsetAsync(pooled, 0, (size_t)NGRAPH * HID * 4, stream);

    k_hist<<<(ETOT + 255) / 256, 256, 0, stream>>>(ei, deg);
    k_scan<<<1, 1024, 0, stream>>>(deg, csr_off);
    k_scatter<<<(ETOT + 255) / 256, 256, 0, stream>>>(ei, csr_off, cur, csr_src);
    k_bounds<<<(N_NODES + 255) / 256, 256, 0, stream>>>(batch, gstart);
    k_wconv<<<(LAYERS * 32 * 4 * 64 * 8) / 256, 256, 0, stream>>>(gat_W, wswz);

    k_inproj<<<(N_NODES + 1) / 2, 256, 0, stream>>>(x, W_in, b_in, h, hb);

    for (int l = 0; l < LAYERS; ++l) {
        k_gemm<<<dim3(N_PAD / 64, HEADS), 256, 0, stream>>>(
            hb, wswz + (size_t)l * HID * FTOT,
            att_src + (size_t)l * HEADS * HID, att_dst + (size_t)l * HEADS * HID,
            xl, al_s, al_d);
        k_agg<<<N_NODES / 2, 256, 0, stream>>>(
            xl, al_s, al_d, csr_off, csr_src, gat_b + (size_t)l * HID, h, hb);
    }

    k_pool<<<dim3(32, NGRAPH), 128, 0, stream>>>(h, gstart, pooled);
    k_mlp<<<NGRAPH, 256, 0, stream>>>(pooled, gstart, W1, b1, W2, b2, W3, b3, out);
}

// Round 9
// 366.515 us; speedup vs baseline: 1.1000x; 1.1000x over previous
//
#include <hip/hip_runtime.h>

#define N_NODES 20000
#define N_PAD   20032            // 313 * 64
#define N_EDGES 200000
#define ETOT    (N_EDGES + N_NODES)
#define F_IN    20
#define HID     128
#define HEADS   4
#define FTOT    (HEADS * HID)   // 512
#define LAYERS  4
#define NGRAPH  32
#define NEG_SLOPE 0.2f
#define DEG_CAP 64

typedef __attribute__((ext_vector_type(8))) unsigned short ushortx8;
typedef __attribute__((ext_vector_type(8))) short short8;
typedef __attribute__((ext_vector_type(4))) float f32x4;

static __device__ __forceinline__ unsigned short f2bf(float f) {
    unsigned u = __float_as_uint(f);
    u += 0x7FFFu + ((u >> 16) & 1u);   // round-to-nearest-even
    return (unsigned short)(u >> 16);
}
static __device__ __forceinline__ float bf2f(unsigned short s) {
    return __uint_as_float(((unsigned)s) << 16);
}

// ---------------- CSR build (dst is layer-invariant) ----------------

__global__ void k_hist(const int* __restrict__ ei, int* __restrict__ deg) {
    int i = blockIdx.x * blockDim.x + threadIdx.x;
    if (i >= ETOT) return;
    int d = (i < N_EDGES) ? ei[N_EDGES + i] : (i - N_EDGES);
    atomicAdd(&deg[d], 1);
}

__global__ __launch_bounds__(1024) void k_scan(const int* __restrict__ deg, int* __restrict__ off) {
    __shared__ int wsum[16];
    __shared__ int carry_s;
    int tid  = threadIdx.x;
    int lane = tid & 63, wv = tid >> 6;
    if (tid == 0) carry_s = 0;
    __syncthreads();
    for (int base = 0; base < N_NODES; base += 1024) {
        int idx = base + tid;
        int v = (idx < N_NODES) ? deg[idx] : 0;
        int x = v;
        #pragma unroll
        for (int s = 1; s < 64; s <<= 1) {
            int t = __shfl_up(x, s, 64);
            if (lane >= s) x += t;
        }
        if (lane == 63) wsum[wv] = x;
        __syncthreads();
        if (wv == 0) {
            int ws = (lane < 16) ? wsum[lane] : 0;
            #pragma unroll
            for (int s = 1; s < 16; s <<= 1) {
                int t = __shfl_up(ws, s, 64);
                if (lane >= s) ws += t;
            }
            if (lane < 16) wsum[lane] = ws;
        }
        __syncthreads();
        int wprev = (wv == 0) ? 0 : wsum[wv - 1];
        int incl  = carry_s + wprev + x;
        if (idx < N_NODES) off[idx] = incl - v;
        __syncthreads();
        if (tid == 1023) carry_s = incl;
        __syncthreads();
    }
    if (threadIdx.x == 0) off[N_NODES] = carry_s;
}

__global__ void k_scatter(const int* __restrict__ ei, const int* __restrict__ off,
                          int* __restrict__ cur, int* __restrict__ csr_src) {
    int i = blockIdx.x * blockDim.x + threadIdx.x;
    if (i >= ETOT) return;
    int s, d;
    if (i < N_EDGES) { s = ei[i]; d = ei[N_EDGES + i]; }
    else             { s = d = i - N_EDGES; }
    int pos = off[d] + atomicAdd(&cur[d], 1);
    csr_src[pos] = s;
}

// ---------------- graph boundaries (batch is sorted): no atomics ----------------

__global__ void k_bounds(const int* __restrict__ batch, int* __restrict__ gstart) {
    int i = blockIdx.x * blockDim.x + threadIdx.x;
    if (i >= N_NODES) return;
    int b = batch[i];
    int prev = (i == 0) ? -1 : batch[i - 1];
    for (int g = prev + 1; g <= b; ++g) gstart[g] = i;
    if (i == N_NODES - 1) {
        for (int g = b + 1; g <= NGRAPH; ++g) gstart[g] = N_NODES;
    }
}

// ---------------- W pre-swizzle: gat_W fp32 -> bf16 MFMA-fragment order ----------------

__global__ void k_wconv(const float* __restrict__ W, unsigned short* __restrict__ wswz) {
    int o = blockIdx.x * 256 + threadIdx.x;
    if (o >= LAYERS * 32 * 4 * 64 * 8) return;
    int e    = o & 7;
    int lane = (o >> 3) & 63;
    int kc   = (o >> 9) & 3;
    int cg   = (o >> 11) & 31;
    int l    = o >> 16;
    int k    = kc * 32 + (lane >> 4) * 8 + e;
    int col  = cg * 16 + (lane & 15);
    wswz[o] = f2bf(W[((size_t)l * HID + k) * FTOT + col]);
}

// ---------------- input projection: h = relu(x @ W_in + b_in), + bf16 shadow ----------------

__global__ __launch_bounds__(256) void k_inproj(const float* __restrict__ x,
                                                const float* __restrict__ W,
                                                const float* __restrict__ b,
                                                float* __restrict__ h,
                                                unsigned short* __restrict__ hb) {
    __shared__ float xs[2][F_IN];
    int tid = threadIdx.x;
    int node0 = blockIdx.x * 2;
    if (tid < 2 * F_IN) {
        int r = tid / F_IN, k = tid % F_IN;
        int nd = node0 + r;
        xs[r][k] = (nd < N_NODES) ? x[nd * F_IN + k] : 0.f;
    }
    __syncthreads();
    int ln = tid >> 7;
    int c  = tid & 127;
    int node = node0 + ln;
    if (node >= N_NODES) return;
    float s = b[c];
    #pragma unroll
    for (int k = 0; k < F_IN; ++k) s += xs[ln][k] * W[k * HID + c];
    float r = fmaxf(s, 0.f);
    h[(size_t)node * HID + c] = r;
    hb[(size_t)node * HID + c] = f2bf(r);
}

// ---------------- GEMM (MFMA) + fused attention dots ----------------
// grid (N_PAD/64, HEADS); block 256 = 4 waves; wave w: rows [bx*64+w*16,+16),
// cols [hd*128, +128). al_s/al_d written by plain stores.

__global__ __launch_bounds__(256) void k_gemm(const unsigned short* __restrict__ hb,
                                              const unsigned short* __restrict__ wswz,
                                              const float* __restrict__ asrc,
                                              const float* __restrict__ adst,
                                              unsigned short* __restrict__ xl,
                                              float* __restrict__ al_s,
                                              float* __restrict__ al_d) {
    int tid  = threadIdx.x;
    int lane = tid & 63;
    int w    = tid >> 6;
    int r0   = blockIdx.x * 64 + w * 16;
    int hd   = blockIdx.y;
    int arow = r0 + (lane & 15);
    const short8* ap = (const short8*)(hb + (size_t)arow * HID + (lane >> 4) * 8);
    const short8* bp = (const short8*)wswz;
    short8 a[4];
    #pragma unroll
    for (int kc = 0; kc < 4; ++kc) a[kc] = ap[kc * 4];   // kc*32 channels
    f32x4 acc[8];
    #pragma unroll
    for (int ct = 0; ct < 8; ++ct) {
        f32x4 c = {0.f, 0.f, 0.f, 0.f};
        int cg = hd * 8 + ct;
        #pragma unroll
        for (int kc = 0; kc < 4; ++kc) {
            short8 b = bp[(cg * 4 + kc) * 64 + lane];
            c = __builtin_amdgcn_mfma_f32_16x16x32_bf16(a[kc], b, c, 0, 0, 0);
        }
        acc[ct] = c;
    }
    int ocol = lane & 15;
    int orow = r0 + (lane >> 4) * 4;
    float vs[4] = {}, vd[4] = {};
    #pragma unroll
    for (int ct = 0; ct < 8; ++ct) {
        int colg = hd * 128 + ct * 16 + ocol;
        float as = asrc[colg], ad = adst[colg];
        #pragma unroll
        for (int r = 0; r < 4; ++r) {
            vs[r] += acc[ct][r] * as;
            vd[r] += acc[ct][r] * ad;
            int row = orow + r;
            if (row < N_NODES) xl[(size_t)row * FTOT + colg] = f2bf(acc[ct][r]);
        }
    }
    #pragma unroll
    for (int msk = 1; msk < 16; msk <<= 1) {
        #pragma unroll
        for (int r = 0; r < 4; ++r) {
            vs[r] += __shfl_xor(vs[r], msk, 64);
            vd[r] += __shfl_xor(vd[r], msk, 64);
        }
    }
    if (ocol == 0) {
        #pragma unroll
        for (int r = 0; r < 4; ++r) {
            int row = orow + r;
            if (row < N_NODES) {
                al_s[row * HEADS + hd] = vs[r];
                al_d[row * HEADS + hd] = vd[r];
            }
        }
    }
}

// ---------------- edge aggregation ----------------
// 1 wave per node (4 nodes/block). Pass A: 16 edge-lanes x 4 head-groups
// compute ev, keep in named regs, butterfly (m,z), store p=exp(ev-m) to LDS.
// Pass B: pure gather -- ds_read p (broadcast) + 16B ushortx8 load + 8 FMA,
// unrolled x2. zinv folded into epilogue.

__global__ __launch_bounds__(256) void k_agg(const unsigned short* __restrict__ xl,
                                             const float* __restrict__ al_s,
                                             const float* __restrict__ al_d,
                                             const int* __restrict__ csr_off,
                                             const int* __restrict__ csr_src,
                                             const float* __restrict__ bias,
                                             float* __restrict__ h,
                                             unsigned short* __restrict__ hb) {
    __shared__ float alds[4][DEG_CAP][HEADS];   // [node][edge][head] -> conflict-light
    int tid  = threadIdx.x;
    int lane = tid & 63;
    int wid  = tid >> 6;
    int node = blockIdx.x * 4 + wid;
    if (node >= N_NODES) return;
    int hh = lane >> 4;
    int el = lane & 15;
    int e0 = csr_off[node], e1 = csr_off[node + 1];
    int deg = e1 - e0;
    float ald = al_d[node * HEADS + hh];

    // ---- pass A ----
    float ev0 = -1e30f, ev1 = -1e30f, ev2 = -1e30f, ev3 = -1e30f;
    {
        if (el < deg) {
            int s = csr_src[e0 + el];
            float e = al_s[s * HEADS + hh] + ald;
            ev0 = e > 0.f ? e : NEG_SLOPE * e;
        }
        if (el + 16 < deg) {
            int s = csr_src[e0 + el + 16];
            float e = al_s[s * HEADS + hh] + ald;
            ev1 = e > 0.f ? e : NEG_SLOPE * e;
        }
        if (el + 32 < deg) {
            int s = csr_src[e0 + el + 32];
            float e = al_s[s * HEADS + hh] + ald;
            ev2 = e > 0.f ? e : NEG_SLOPE * e;
        }
        if (el + 48 < deg) {
            int s = csr_src[e0 + el + 48];
            float e = al_s[s * HEADS + hh] + ald;
            ev3 = e > 0.f ? e : NEG_SLOPE * e;
        }
    }
    float m = fmaxf(fmaxf(ev0, ev1), fmaxf(ev2, ev3));
    float z = 0.f;
    if (el      < deg) z += __expf(ev0 - m);
    if (el + 16 < deg) z += __expf(ev1 - m);
    if (el + 32 < deg) z += __expf(ev2 - m);
    if (el + 48 < deg) z += __expf(ev3 - m);
    // rare tail deg > 64 (never for this graph, but correct)
    for (int i = el + DEG_CAP; i < deg; i += 16) {
        int s = csr_src[e0 + i];
        float e = al_s[s * HEADS + hh] + ald;
        e = e > 0.f ? e : NEG_SLOPE * e;
        float mn = fmaxf(m, e);
        z = z * __expf(m - mn) + __expf(e - mn);
        m = mn;
    }
    #pragma unroll
    for (int msk = 1; msk < 16; msk <<= 1) {
        float m2 = __shfl_xor(m, msk, 64);
        float z2 = __shfl_xor(z, msk, 64);
        float mn = fmaxf(m, m2);
        z = z * __expf(m - mn) + z2 * __expf(m2 - mn);
        m = mn;
    }
    float zinv = 1.f / (z + 1e-16f);
    if (el      < deg) alds[wid][el     ][hh] = __expf(ev0 - m);
    if (el + 16 < deg) alds[wid][el + 16][hh] = __expf(ev1 - m);
    if (el + 32 < deg) alds[wid][el + 32][hh] = __expf(ev2 - m);
    if (el + 48 < deg) alds[wid][el + 48][hh] = __expf(ev3 - m);
    __syncthreads();

    // ---- pass B ----
    float acc[8] = {};
    const unsigned short* xbase = xl + lane * 8;
    int dcap = deg < DEG_CAP ? deg : DEG_CAP;
    int i = 0;
    for (; i + 1 < dcap; i += 2) {
        int s0 = csr_src[e0 + i];
        int s1 = csr_src[e0 + i + 1];
        float a0 = alds[wid][i][hh];
        float a1 = alds[wid][i + 1][hh];
        ushortx8 v0 = *(const ushortx8*)(xbase + (size_t)s0 * FTOT);
        ushortx8 v1 = *(const ushortx8*)(xbase + (size_t)s1 * FTOT);
        #pragma unroll
        for (int j = 0; j < 8; ++j) acc[j] += a0 * bf2f(v0[j]) + a1 * bf2f(v1[j]);
    }
    if (i < dcap) {
        int s0 = csr_src[e0 + i];
        float a0 = alds[wid][i][hh];
        ushortx8 v0 = *(const ushortx8*)(xbase + (size_t)s0 * FTOT);
        #pragma unroll
        for (int j = 0; j < 8; ++j) acc[j] += a0 * bf2f(v0[j]);
    }
    for (int t = DEG_CAP; t < deg; ++t) {       // rare tail
        int s0 = csr_src[e0 + t];
        float e = al_s[s0 * HEADS + hh] + ald;
        e = e > 0.f ? e : NEG_SLOPE * e;
        float a0 = __expf(e - m);
        ushortx8 v0 = *(const ushortx8*)(xbase + (size_t)s0 * FTOT);
        #pragma unroll
        for (int j = 0; j < 8; ++j) acc[j] += a0 * bf2f(v0[j]);
    }
    #pragma unroll
    for (int j = 0; j < 8; ++j) {
        acc[j] *= zinv;
        acc[j] += __shfl_xor(acc[j], 16, 64);
        acc[j] += __shfl_xor(acc[j], 32, 64);
    }
    if (lane < 16) {
        int c = lane * 8;
        float4 hv0 = *(const float4*)(h + (size_t)node * HID + c);
        float4 hv1 = *(const float4*)(h + (size_t)node * HID + c + 4);
        float4 b0 = *(const float4*)(bias + c);
        float4 b1 = *(const float4*)(bias + c + 4);
        float o0 = fmaxf(acc[0] * 0.25f + b0.x, 0.f) + hv0.x;
        float o1 = fmaxf(acc[1] * 0.25f + b0.y, 0.f) + hv0.y;
        float o2 = fmaxf(acc[2] * 0.25f + b0.z, 0.f) + hv0.z;
        float o3 = fmaxf(acc[3] * 0.25f + b0.w, 0.f) + hv0.w;
        float o4 = fmaxf(acc[4] * 0.25f + b1.x, 0.f) + hv1.x;
        float o5 = fmaxf(acc[5] * 0.25f + b1.y, 0.f) + hv1.y;
        float o6 = fmaxf(acc[6] * 0.25f + b1.z, 0.f) + hv1.z;
        float o7 = fmaxf(acc[7] * 0.25f + b1.w, 0.f) + hv1.w;
        *(float4*)(h + (size_t)node * HID + c)     = make_float4(o0, o1, o2, o3);
        *(float4*)(h + (size_t)node * HID + c + 4) = make_float4(o4, o5, o6, o7);
        ushortx8 hv;
        hv[0] = f2bf(o0); hv[1] = f2bf(o1); hv[2] = f2bf(o2); hv[3] = f2bf(o3);
        hv[4] = f2bf(o4); hv[5] = f2bf(o5); hv[6] = f2bf(o6); hv[7] = f2bf(o7);
        *(ushortx8*)(hb + (size_t)node * HID + c) = hv;
    }
}

// ---------------- pooling + MLP ----------------

__global__ __launch_bounds__(128) void k_pool(const float* __restrict__ h,
                                              const int* __restrict__ gstart,
                                              float* __restrict__ pooled) {
    int g = blockIdx.y;
    int slice = blockIdx.x;      // 0..31
    int tid = threadIdx.x;       // 0..127
    int start = gstart[g];
    int cnt   = gstart[g + 1] - start;
    int per = (cnt + 31) / 32;
    int r0 = slice * per, r1 = min(r0 + per, cnt);
    if (r0 >= r1) return;
    float s0 = 0.f, s1 = 0.f, s2 = 0.f, s3 = 0.f;
    int r = r0;
    for (; r + 3 < r1; r += 4) {
        s0 += h[(size_t)(start + r)     * HID + tid];
        s1 += h[(size_t)(start + r + 1) * HID + tid];
        s2 += h[(size_t)(start + r + 2) * HID + tid];
        s3 += h[(size_t)(start + r + 3) * HID + tid];
    }
    for (; r < r1; ++r) s0 += h[(size_t)(start + r) * HID + tid];
    atomicAdd(&pooled[g * HID + tid], (s0 + s1) + (s2 + s3));
}

__global__ __launch_bounds__(256) void k_mlp(const float* __restrict__ pooled,
                                             const int* __restrict__ gstart,
                                             const float* __restrict__ W1, const float* __restrict__ b1,
                                             const float* __restrict__ W2, const float* __restrict__ b2,
                                             const float* __restrict__ W3, const float* __restrict__ b3,
                                             float* __restrict__ out) {
    int gr = blockIdx.x;
    __shared__ float g[HID];
    __shared__ float part[4][64];
    __shared__ float t1[64], t2[64];
    int tid = threadIdx.x;
    if (tid < HID) {
        float inv = 1.f / fmaxf((float)(gstart[gr + 1] - gstart[gr]), 1.f);
        g[tid] = pooled[gr * HID + tid] * inv;
    }
    __syncthreads();
    {
        int c = tid & 63, q = tid >> 6;
        float s = 0.f;
        #pragma unroll 8
        for (int k = q * 32; k < q * 32 + 32; ++k) s += g[k] * W1[k * 64 + c];
        part[q][c] = s;
        __syncthreads();
        if (tid < 64) t1[tid] = fmaxf(part[0][tid] + part[1][tid] + part[2][tid] + part[3][tid] + b1[tid], 0.f);
        __syncthreads();
    }
    {
        int c = tid & 63, q = tid >> 6;
        float s = 0.f;
        #pragma unroll 8
        for (int k = q * 16; k < q * 16 + 16; ++k) s += t1[k] * W2[k * 64 + c];
        part[q][c] = s;
        __syncthreads();
        if (tid < 64) t2[tid] = fmaxf(part[0][tid] + part[1][tid] + part[2][tid] + part[3][tid] + b2[tid], 0.f);
        __syncthreads();
    }
    {
        int c = tid & 31, q = tid >> 5;
        float s = 0.f;
        #pragma unroll 8
        for (int k = q * 8; k < q * 8 + 8; ++k) s += t2[k] * W3[k * 32 + c];
        float* pf = &part[0][0];
        pf[q * 32 + c] = s;
        __syncthreads();
        if (tid < 32) {
            float r = b3[tid];
            #pragma unroll
            for (int q2 = 0; q2 < 8; ++q2) r += pf[q2 * 32 + tid];
            out[gr * 32 + tid] = r;
        }
    }
}

// ---------------- launcher ----------------

extern "C" void kernel_launch(void* const* d_in, const int* in_sizes, int n_in,
                              void* d_out, int out_size, void* d_ws, size_t ws_size,
                              hipStream_t stream) {
    const float* x       = (const float*)d_in[0];
    const int*   ei      = (const int*)d_in[1];
    const int*   batch   = (const int*)d_in[2];
    const float* W_in    = (const float*)d_in[3];
    const float* b_in    = (const float*)d_in[4];
    const float* gat_W   = (const float*)d_in[5];
    const float* att_src = (const float*)d_in[6];
    const float* att_dst = (const float*)d_in[7];
    const float* gat_b   = (const float*)d_in[8];
    const float* W1 = (const float*)d_in[9];
    const float* b1 = (const float*)d_in[10];
    const float* W2 = (const float*)d_in[11];
    const float* b2 = (const float*)d_in[12];
    const float* W3 = (const float*)d_in[13];
    const float* b3 = (const float*)d_in[14];
    float* out = (float*)d_out;

    char* ws = (char*)d_ws;
    size_t o = 0;
    auto alloc = [&](size_t nbytes) -> void* {
        void* p = ws + o;
        o += (nbytes + 255) & ~(size_t)255;
        return p;
    };
    int* deg      = (int*)alloc((size_t)2 * N_NODES * 4);      // deg | cur
    int* cur      = deg + N_NODES;
    int* gstart   = (int*)alloc((size_t)(NGRAPH + 1) * 4);
    float* pooled = (float*)alloc((size_t)NGRAPH * HID * 4);
    int* csr_off  = (int*)alloc((size_t)(N_NODES + 1) * 4);
    int* csr_src  = (int*)alloc((size_t)ETOT * 4);
    float* h      = (float*)alloc((size_t)N_NODES * HID * 4);
    unsigned short* hb   = (unsigned short*)alloc((size_t)N_PAD * HID * 2);
    unsigned short* xl   = (unsigned short*)alloc((size_t)N_NODES * FTOT * 2);
    unsigned short* wswz = (unsigned short*)alloc((size_t)LAYERS * HID * FTOT * 2);
    float* al_s   = (float*)alloc((size_t)N_NODES * HEADS * 4);
    float* al_d   = (float*)alloc((size_t)N_NODES * HEADS * 4);

    hipMemsetAsync(deg, 0, (size_t)2 * N_NODES * 4, stream);
    hipMemsetAsync(pooled, 0, (size_t)NGRAPH * HID * 4, stream);

    k_hist<<<(ETOT + 255) / 256, 256, 0, stream>>>(ei, deg);
    k_scan<<<1, 1024, 0, stream>>>(deg, csr_off);
    k_scatter<<<(ETOT + 255) / 256, 256, 0, stream>>>(ei, csr_off, cur, csr_src);
    k_bounds<<<(N_NODES + 255) / 256, 256, 0, stream>>>(batch, gstart);
    k_wconv<<<(LAYERS * 32 * 4 * 64 * 8) / 256, 256, 0, stream>>>(gat_W, wswz);

    k_inproj<<<(N_NODES + 1) / 2, 256, 0, stream>>>(x, W_in, b_in, h, hb);

    for (int l = 0; l < LAYERS; ++l) {
        k_gemm<<<dim3(N_PAD / 64, HEADS), 256, 0, stream>>>(
            hb, wswz + (size_t)l * HID * FTOT,
            att_src + (size_t)l * HEADS * HID, att_dst + (size_t)l * HEADS * HID,
            xl, al_s, al_d);
        k_agg<<<(N_NODES + 3) / 4, 256, 0, stream>>>(
            xl, al_s, al_d, csr_off, csr_src, gat_b + (size_t)l * HID, h, hb);
    }

    k_pool<<<dim3(32, NGRAPH), 128, 0, stream>>>(h, gstart, pooled);
    k_mlp<<<NGRAPH, 256, 0, stream>>>(pooled, gstart, W1, b1, W2, b2, W3, b3, out);
}